// Round 16
// baseline (479.775 us; speedup 1.0000x reference)
//
#include <hip/hip_runtime.h>
#include <hip/hip_bf16.h>
#include <math.h>

#define NN 50000
#define EE 400000
#define D_IN 256
#define D_H 64
#define N_CLS 50

typedef __attribute__((ext_vector_type(8))) short bfrag;   // 8 bf16 (4 VGPR)
typedef __attribute__((ext_vector_type(4))) float ffrag;   // MFMA C/D
typedef __attribute__((ext_vector_type(8))) unsigned short u16x8_t;
typedef __attribute__((ext_vector_type(4))) unsigned short u16x4_t;

__device__ __forceinline__ unsigned short f2bf(float v) {
    unsigned int u = __float_as_uint(v);
    unsigned int r = (u + 0x7fffu + ((u >> 16) & 1u)) >> 16;   // RNE
    return (unsigned short)r;
}
__device__ __forceinline__ float bf2f(unsigned short b) {
    return __uint_as_float(((unsigned int)b) << 16);
}

// XOR sub-chunk swizzle (r7/r10-verified: 0 bank conflicts). row stride 32
// shorts (64B, unpadded); q = 8-short chunk 0..3. 16B-aligned offsets.
__device__ __forceinline__ int swz(int row, int q) {
    return row * 32 + ((q ^ ((row >> 1) & 3)) << 3);
}

// ---------------------------------------------------------------------------
// CSR construction — parallel 3-phase scan (verified r7)
// ---------------------------------------------------------------------------
__global__ void count_k(const int* __restrict__ ei, int* __restrict__ cnt, int E, int N) {
    int i = blockIdx.x * blockDim.x + threadIdx.x;
    if (i >= E + N) return;
    int dst = (i < E) ? ei[E + i] : (i - E);
    atomicAdd(&cnt[dst], 1);
}

__global__ __launch_bounds__(1024) void scan1_k(const int* __restrict__ counts,
                                                int* __restrict__ excl,
                                                int* __restrict__ bsum, int n) {
    __shared__ int wsum[16];
    int t = threadIdx.x;
    int lane = t & 63, wid = t >> 6;
    int idx = blockIdx.x * 1024 + t;
    int v = (idx < n) ? counts[idx] : 0;
    int incl = v;
    #pragma unroll
    for (int off = 1; off < 64; off <<= 1) {
        int x = __shfl_up(incl, off);
        if (lane >= off) incl += x;
    }
    if (lane == 63) wsum[wid] = incl;
    __syncthreads();
    if (wid == 0) {
        int ws = (lane < 16) ? wsum[lane] : 0;
        int wincl = ws;
        #pragma unroll
        for (int off = 1; off < 16; off <<= 1) {
            int x = __shfl_up(wincl, off);
            if (lane >= off) wincl += x;
        }
        if (lane < 16) wsum[lane] = wincl - ws;   // exclusive wave prefix
    }
    __syncthreads();
    if (idx < n) excl[idx] = wsum[wid] + (incl - v);
    if (t == 1023) bsum[blockIdx.x] = wsum[15] + incl;
}

__global__ void scan2_k(int* __restrict__ bsum, int nb) {
    int lane = threadIdx.x & 63;
    int v = (lane < nb) ? bsum[lane] : 0;
    int incl = v;
    #pragma unroll
    for (int off = 1; off < 64; off <<= 1) {
        int x = __shfl_up(incl, off);
        if (lane >= off) incl += x;
    }
    if (lane < nb) bsum[lane] = incl - v;
}

__global__ void scan3_k(const int* __restrict__ excl, const int* __restrict__ bsum,
                        int* __restrict__ rowptr, int n, int total) {
    int i = blockIdx.x * 256 + threadIdx.x;
    if (i < n) rowptr[i] = excl[i] + bsum[i >> 10];
    if (i == 0) rowptr[n] = total;
}

__global__ void fill_k(const int* __restrict__ ei, const int* __restrict__ rowptr,
                       int* __restrict__ cursor, int* __restrict__ csr, int E, int N) {
    int i = blockIdx.x * blockDim.x + threadIdx.x;
    if (i >= E + N) return;
    int s, d;
    if (i < E) { s = ei[i]; d = ei[E + i]; }
    else       { s = i - E; d = i - E; }
    int pos = atomicAdd(&cursor[d], 1);
    csr[rowptr[d] + pos] = s;
}

// ---------------------------------------------------------------------------
// prep_k: blocks 0..63 — Wc = W3@cW1, bc = b3@cW1+cb1, w_as3/w_ad3 = W3@as3/ad3
// (agg/GEMM commute, verified r13); block 64/65 — BN folds for layers 1/2.
// ---------------------------------------------------------------------------
__global__ __launch_bounds__(64) void prep_k(
    const float* __restrict__ W3, const float* __restrict__ cW1,
    const float* __restrict__ as3, const float* __restrict__ ad3,
    const float* __restrict__ b3, const float* __restrict__ cb1,
    const float* __restrict__ bn1g, const float* __restrict__ bn1b,
    const float* __restrict__ bn1m, const float* __restrict__ bn1v,
    const float* __restrict__ b1,
    const float* __restrict__ bn2g, const float* __restrict__ bn2b,
    const float* __restrict__ bn2m, const float* __restrict__ bn2v,
    const float* __restrict__ b2,
    float* __restrict__ Wc, float* __restrict__ w_as3,
    float* __restrict__ w_ad3, float* __restrict__ bc,
    float* __restrict__ sc1, float* __restrict__ sh1,
    float* __restrict__ sc2, float* __restrict__ sh2) {
    int bj = blockIdx.x;
    int i = threadIdx.x;
    if (bj < 64) {
        int j = bj;
        float s = 0.f;
        for (int k = 0; k < 64; k++) s += W3[i * 64 + k] * cW1[k * 64 + j];
        Wc[i * 64 + j] = s;
        if (j == 0) {
            float sa = 0.f, sd = 0.f;
            for (int c = 0; c < 64; c++) {
                sa += W3[i * 64 + c] * as3[c];
                sd += W3[i * 64 + c] * ad3[c];
            }
            w_as3[i] = sa;
            w_ad3[i] = sd;
        }
        if (i == 0) {
            float s2 = 0.f;
            for (int k = 0; k < 64; k++) s2 += b3[k] * cW1[k * 64 + j];
            bc[j] = s2 + cb1[j];
        }
    } else if (bj == 64) {
        float sc = bn1g[i] * rsqrtf(bn1v[i] + 1e-5f);
        sc1[i] = sc;
        sh1[i] = (b1[i] - bn1m[i]) * sc + bn1b[i];
    } else {
        float sc = bn2g[i] * rsqrtf(bn2v[i] + 1e-5f);
        sc2[i] = sc;
        sh2[i] = (b2[i] - bn2m[i]) * sc + bn2b[i];
    }
}

// ---------------------------------------------------------------------------
// cvt_all_k: one launch converts x (row-major, no transpose) + all 4 weight
// matrices (to split-bf16 B^T). Segments: x (50000x256), W1 (256x512),
// W2 (64x256), Wc (64x64), cW2 (64x50).
// ---------------------------------------------------------------------------
#define S_X  (NN * 256)
#define S_W1 (S_X + 131072)
#define S_W2 (S_W1 + 16384)
#define S_WC (S_W2 + 4096)
#define S_WL (S_WC + 3200)
__global__ void cvt_all_k(
    const float* __restrict__ x,
    const float* __restrict__ W1, const float* __restrict__ W2,
    const float* __restrict__ Wc, const float* __restrict__ cW2,
    unsigned short* __restrict__ xh, unsigned short* __restrict__ xl,
    unsigned short* __restrict__ w1h, unsigned short* __restrict__ w1l,
    unsigned short* __restrict__ w2h, unsigned short* __restrict__ w2l,
    unsigned short* __restrict__ wch, unsigned short* __restrict__ wcl,
    unsigned short* __restrict__ wlh, unsigned short* __restrict__ wll) {
    int i = blockIdx.x * 256 + threadIdx.x;
    if (i < S_X) {
        float v = x[i];
        unsigned short h = f2bf(v);
        xh[i] = h;
        xl[i] = f2bf(v - bf2f(h));
        return;
    }
    const float* src; unsigned short* dh; unsigned short* dl;
    int K, Nn, j;
    if (i < S_W1)      { j = i - S_X;  src = W1;  dh = w1h; dl = w1l; K = 256; Nn = 512; }
    else if (i < S_W2) { j = i - S_W1; src = W2;  dh = w2h; dl = w2l; K = 64;  Nn = 256; }
    else if (i < S_WC) { j = i - S_W2; src = Wc;  dh = wch; dl = wcl; K = 64;  Nn = 64;  }
    else if (i < S_WL) { j = i - S_WC; src = cW2; dh = wlh; dl = wll; K = 64;  Nn = 50;  }
    else return;
    int k = j / Nn, n = j - k * Nn;
    float v = src[j];
    unsigned short h = f2bf(v);
    dh[(size_t)n * K + k] = h;
    dl[(size_t)n * K + k] = f2bf(v - bf2f(h));
}

// ---------------------------------------------------------------------------
// Split-bf16 MFMA GEMM (r11-verified structure — pre-converted bf16 A only;
// the fused fp32-A path measured slower in r13-r15 and is removed).
// 64x128 tile, BK=32, 4 waves 2x2, conflict-free XOR LDS. Fused epilogues:
// fp32/bf16(+lo) C, bias+ReLU, attention scores from raw accumulators.
// ---------------------------------------------------------------------------
__global__ __launch_bounds__(256) void gemm_mfma_k(
    const unsigned short* __restrict__ Ahi, const unsigned short* __restrict__ Alo,
    const unsigned short* __restrict__ BThi, const unsigned short* __restrict__ BTlo,
    float* __restrict__ Cf, unsigned short* __restrict__ Chi, unsigned short* __restrict__ Clo,
    int M, int N, int K,
    const float* __restrict__ bias, int do_relu,
    const float* __restrict__ att_s, const float* __restrict__ att_d,
    float* __restrict__ asb, float* __restrict__ adb, int H) {
    __shared__ unsigned short sAh[64 * 32];
    __shared__ unsigned short sAl[64 * 32];
    __shared__ unsigned short sBh[128 * 32];
    __shared__ unsigned short sBl[128 * 32];
    const int tid = threadIdx.x;
    const int m0 = blockIdx.y * 64;
    const int n0 = blockIdx.x * 128;
    const int lane = tid & 63, w = tid >> 6;
    const int wm = w >> 1, wn = w & 1;
    const int c16 = lane & 15, kq = lane >> 4;
    const int arow = tid >> 2;          // 0..63
    const int q    = tid & 3;           // 8-short chunk 0..3
    const int akc  = q * 8;
    const int aM  = min(m0 + arow, M - 1);
    const int bn0 = min(n0 + arow, N - 1);
    const int bn1 = min(n0 + 64 + arow, N - 1);
    const int wA  = swz(arow, q);
    const int wB0 = swz(arow, q);
    const int wB1 = swz(64 + arow, q);
    const unsigned short* pAh = Ahi + (size_t)aM * K + akc;
    const unsigned short* pAl = Alo + (size_t)aM * K + akc;
    const unsigned short* pBh0 = BThi + (size_t)bn0 * K + akc;
    const unsigned short* pBl0 = BTlo + (size_t)bn0 * K + akc;
    const unsigned short* pBh1 = BThi + (size_t)bn1 * K + akc;
    const unsigned short* pBl1 = BTlo + (size_t)bn1 * K + akc;
    ffrag acc[2][4] = {};

    for (int k0 = 0; k0 < K; k0 += 32) {
        bfrag va_h  = *(const bfrag*)(pAh + k0);
        bfrag va_l  = *(const bfrag*)(pAl + k0);
        bfrag vb_h0 = *(const bfrag*)(pBh0 + k0);
        bfrag vb_l0 = *(const bfrag*)(pBl0 + k0);
        bfrag vb_h1 = *(const bfrag*)(pBh1 + k0);
        bfrag vb_l1 = *(const bfrag*)(pBl1 + k0);
        __syncthreads();
        *(bfrag*)&sAh[wA]  = va_h;
        *(bfrag*)&sAl[wA]  = va_l;
        *(bfrag*)&sBh[wB0] = vb_h0;
        *(bfrag*)&sBl[wB0] = vb_l0;
        *(bfrag*)&sBh[wB1] = vb_h1;
        *(bfrag*)&sBl[wB1] = vb_l1;
        __syncthreads();
        bfrag ah[2], al_[2], bh[4], bl[4];
        #pragma unroll
        for (int mt = 0; mt < 2; mt++) {
            int ra = wm * 32 + mt * 16 + c16;
            ah[mt]  = *(const bfrag*)&sAh[swz(ra, kq)];
            al_[mt] = *(const bfrag*)&sAl[swz(ra, kq)];
        }
        #pragma unroll
        for (int nt = 0; nt < 4; nt++) {
            int rb = wn * 64 + nt * 16 + c16;
            bh[nt] = *(const bfrag*)&sBh[swz(rb, kq)];
            bl[nt] = *(const bfrag*)&sBl[swz(rb, kq)];
        }
        #pragma unroll
        for (int mt = 0; mt < 2; mt++)
            #pragma unroll
            for (int nt = 0; nt < 4; nt++) {
                acc[mt][nt] = __builtin_amdgcn_mfma_f32_16x16x32_bf16(ah[mt],  bh[nt], acc[mt][nt], 0, 0, 0);
                acc[mt][nt] = __builtin_amdgcn_mfma_f32_16x16x32_bf16(ah[mt],  bl[nt], acc[mt][nt], 0, 0, 0);
                acc[mt][nt] = __builtin_amdgcn_mfma_f32_16x16x32_bf16(al_[mt], bh[nt], acc[mt][nt], 0, 0, 0);
            }
    }

    // ---- fused attention scores (raw h, pre-bias/relu; GAT layers only) ----
    if (att_s) {
        int hidx = n0 / 64 + wn;
        if (hidx < H) {
            float s_att[4], d_att[4];
            #pragma unroll
            for (int nt = 0; nt < 4; nt++) {
                s_att[nt] = att_s[hidx * 64 + nt * 16 + c16];
                d_att[nt] = att_d[hidx * 64 + nt * 16 + c16];
            }
            #pragma unroll
            for (int mt = 0; mt < 2; mt++) {
                #pragma unroll
                for (int r = 0; r < 4; r++) {
                    int row = m0 + wm * 32 + mt * 16 + kq * 4 + r;
                    float ps = 0.f, pd = 0.f;
                    #pragma unroll
                    for (int nt = 0; nt < 4; nt++) {
                        ps = fmaf(acc[mt][nt][r], s_att[nt], ps);
                        pd = fmaf(acc[mt][nt][r], d_att[nt], pd);
                    }
                    #pragma unroll
                    for (int msk = 1; msk < 16; msk <<= 1) {
                        ps += __shfl_xor(ps, msk);
                        pd += __shfl_xor(pd, msk);
                    }
                    if (c16 == 0 && row < M) {
                        asb[(size_t)row * H + hidx] = ps;
                        adb[(size_t)row * H + hidx] = pd;
                    }
                }
            }
        }
    }

    // ---- C write ----
    #pragma unroll
    for (int mt = 0; mt < 2; mt++) {
        #pragma unroll
        for (int r = 0; r < 4; r++) {
            int row = m0 + wm * 32 + mt * 16 + kq * 4 + r;
            if (row < M) {
                #pragma unroll
                for (int nt = 0; nt < 4; nt++) {
                    int col = n0 + wn * 64 + nt * 16 + c16;
                    if (col < N) {
                        float v = acc[mt][nt][r];
                        if (bias) v += bias[col];
                        if (do_relu) v = fmaxf(v, 0.f);
                        size_t idx = (size_t)row * N + col;
                        if (Cf) Cf[idx] = v;
                        if (Chi) {
                            unsigned short hh = f2bf(v);
                            Chi[idx] = hh;
                            if (Clo) Clo[idx] = f2bf(v - bf2f(hh));
                        }
                    }
                }
            }
        }
    }
}

__device__ __forceinline__ float wave_max_f(float v) {
    #pragma unroll
    for (int off = 32; off; off >>= 1) v = fmaxf(v, __shfl_xor(v, off));
    return v;
}
__device__ __forceinline__ float wave_sum_f(float v) {
    #pragma unroll
    for (int off = 32; off; off >>= 1) v += __shfl_xor(v, off);
    return v;
}

// ---------------------------------------------------------------------------
// Aggregation (r11/r13-verified): one wave per node, all heads, bf16 gather;
// (edge,head)-parallel softmax, deferred normalization; optional fused
// next-layer attention scores; optional null outlo/shift.
// ---------------------------------------------------------------------------
template <int H, bool MEAN_BN>
__global__ __launch_bounds__(256) void agg_k(
    const unsigned short* __restrict__ hfeat,   // [N, H*64] bf16
    const float* __restrict__ a_s, const float* __restrict__ a_d,
    const int* __restrict__ rowptr, const int* __restrict__ csr,
    const float* __restrict__ scale,
    const float* __restrict__ shift,
    unsigned short* __restrict__ outhi, unsigned short* __restrict__ outlo,
    const float* __restrict__ was3, const float* __restrict__ wad3,
    float* __restrict__ as3o, float* __restrict__ ad3o,
    int N) {
    constexpr int OUT = H * 64;
    constexpr int F = H;          // channels per lane (gather phase)
    constexpr int G = 64 / H;     // lanes per head (gather phase)
    constexpr int EPC = 64 / H;   // edges per chunk (softmax phase)
    __shared__ float alpha_s[4][H][65];
    __shared__ int srcb[4][64];
    const int wv = threadIdx.x >> 6;
    const int lane = threadIdx.x & 63;
    const int node = blockIdx.x * 4 + wv;
    if (node >= N) return;        // no __syncthreads in this kernel — safe

    const int row = rowptr[node];
    const int deg = rowptr[node + 1] - row;
    const int hl = lane / G;      // gather-phase head of this lane

    float acc[F] = {};
    float inv = 1.f;

    if (deg <= 64) {
        // ---- softmax phase: lane = (j, h); one exp per lane ----
        const int j8 = lane / H;
        const int h8 = lane % H;
        float adn_own = a_d[(size_t)node * H + h8];
        float psum = 0.f;
        for (int c0 = 0; c0 < deg; c0 += EPC) {
            int jj = c0 + j8;
            if (jj < deg) {
                int s = csr[row + jj];
                if (h8 == 0) srcb[wv][jj] = s;
                float e = a_s[(size_t)s * H + h8] + adn_own;
                e = e > 0.f ? e : 0.2f * e;
                float p = __expf(e);
                alpha_s[wv][h8][jj] = p;
                psum += p;
            }
        }
        #pragma unroll
        for (int msk = H; msk < 64; msk <<= 1)
            psum += __shfl_xor(psum, msk);
        float invd = 1.f / (psum + 1e-16f);      // lane L holds denom of head L%H
        inv = __shfl(invd, hl);                  // lane 'hl' has h8 == hl
        asm volatile("s_waitcnt lgkmcnt(0)" ::: "memory");
        // ---- gather phase ----
        for (int jj = 0; jj < deg; jj++) {
            int ss = srcb[wv][jj];
            float al = alpha_s[wv][hl][jj];
            const unsigned short* rp = hfeat + (size_t)ss * OUT + lane * F;
            if constexpr (F == 8) {
                u16x8_t u = *(const u16x8_t*)rp;
                #pragma unroll
                for (int i = 0; i < 8; i++) acc[i] = fmaf(al, bf2f(u[i]), acc[i]);
            } else if constexpr (F == 4) {
                u16x4_t u = *(const u16x4_t*)rp;
                #pragma unroll
                for (int i = 0; i < 4; i++) acc[i] = fmaf(al, bf2f(u[i]), acc[i]);
            } else {
                acc[0] = fmaf(al, bf2f(rp[0]), acc[0]);
            }
        }
    } else {
        // ---- general path (deg > 64; essentially never for this graph) ----
        float adn[H];
        #pragma unroll
        for (int h = 0; h < H; h++) adn[h] = a_d[(size_t)node * H + h];
        float m[H];
        #pragma unroll
        for (int h = 0; h < H; h++) m[h] = -INFINITY;
        for (int c0 = 0; c0 < deg; c0 += 64) {
            int j = c0 + lane;
            if (j < deg) {
                int s2 = csr[row + j];
                #pragma unroll
                for (int h = 0; h < H; h++) {
                    float e = a_s[(size_t)s2 * H + h] + adn[h];
                    e = e > 0.f ? e : 0.2f * e;
                    m[h] = fmaxf(m[h], e);
                }
            }
        }
        #pragma unroll
        for (int h = 0; h < H; h++) m[h] = wave_max_f(m[h]);
        float dsum[H] = {};
        for (int c0 = 0; c0 < deg; c0 += 64) {
            int j = c0 + lane;
            if (j < deg) {
                int s2 = csr[row + j];
                #pragma unroll
                for (int h = 0; h < H; h++) {
                    float e = a_s[(size_t)s2 * H + h] + adn[h];
                    e = e > 0.f ? e : 0.2f * e;
                    dsum[h] += __expf(e - m[h]);
                }
            }
        }
        float dinv[H];
        #pragma unroll
        for (int h = 0; h < H; h++) dinv[h] = 1.f / (wave_sum_f(dsum[h]) + 1e-16f);
        for (int c0 = 0; c0 < deg; c0 += 64) {
            int j = c0 + lane;
            int cnt = min(64, deg - c0);
            int s = 0;
            if (j < deg) {
                s = csr[row + j];
                #pragma unroll
                for (int h = 0; h < H; h++) {
                    float e = a_s[(size_t)s * H + h] + adn[h];
                    e = e > 0.f ? e : 0.2f * e;
                    alpha_s[wv][h][lane] = __expf(e - m[h]) * dinv[h];
                }
            }
            asm volatile("s_waitcnt lgkmcnt(0)" ::: "memory");
            for (int jj = 0; jj < cnt; jj++) {
                int ss = __builtin_amdgcn_readlane(s, jj);
                float al = alpha_s[wv][hl][jj];
                const unsigned short* rp = hfeat + (size_t)ss * OUT + lane * F;
                if constexpr (F == 8) {
                    u16x8_t u = *(const u16x8_t*)rp;
                    #pragma unroll
                    for (int i = 0; i < 8; i++) acc[i] = fmaf(al, bf2f(u[i]), acc[i]);
                } else if constexpr (F == 4) {
                    u16x4_t u = *(const u16x4_t*)rp;
                    #pragma unroll
                    for (int i = 0; i < 4; i++) acc[i] = fmaf(al, bf2f(u[i]), acc[i]);
                } else {
                    acc[0] = fmaf(al, bf2f(rp[0]), acc[0]);
                }
            }
            asm volatile("s_waitcnt lgkmcnt(0)" ::: "memory");
        }
        inv = 1.f;   // alpha already normalized in this path
    }

    // ---- epilogue: deferred normalization, head-mean, BN, split write ----
    #pragma unroll
    for (int i = 0; i < F; i++) acc[i] *= inv;

    if constexpr (MEAN_BN) {
        #pragma unroll
        for (int i = 0; i < F; i++) {
            #pragma unroll
            for (int msk = G; msk < 64; msk <<= 1)
                acc[i] += __shfl_xor(acc[i], msk);
        }
        const int c0 = (lane < G) ? lane * F : 0;
        float res[F];
        if (lane < G) {
            #pragma unroll
            for (int i = 0; i < F; i++) {
                float v = fmaf(acc[i] * (1.0f / H), scale[c0 + i], shift[c0 + i]);
                res[i] = fmaxf(v, 0.f);
            }
        } else {
            #pragma unroll
            for (int i = 0; i < F; i++) res[i] = 0.f;
        }
        // fused next-layer attention scores from post-BN/ReLU row
        if (was3) {
            float ps = 0.f, pd = 0.f;
            if (lane < G) {
                #pragma unroll
                for (int i = 0; i < F; i++) {
                    ps = fmaf(res[i], was3[c0 + i], ps);
                    pd = fmaf(res[i], wad3[c0 + i], pd);
                }
            }
            #pragma unroll
            for (int msk = 1; msk < G; msk <<= 1) {
                ps += __shfl_xor(ps, msk);
                pd += __shfl_xor(pd, msk);
            }
            if (lane == 0) { as3o[node] = ps; ad3o[node] = pd; }
        }
        if (lane < G) {
            #pragma unroll
            for (int i = 0; i < F; i++) {
                unsigned short hh = f2bf(res[i]);
                outhi[(size_t)node * 64 + c0 + i] = hh;
                if (outlo) outlo[(size_t)node * 64 + c0 + i] = f2bf(res[i] - bf2f(hh));
            }
        }
    } else {
        float v = acc[0] + (shift ? shift[lane] : 0.f);
        unsigned short hh = f2bf(v);
        outhi[(size_t)node * 64 + lane] = hh;
        if (outlo) outlo[(size_t)node * 64 + lane] = f2bf(v - bf2f(hh));
    }
}

// ---------------------------------------------------------------------------
// Softmax over N_CLS logits, wave per node.
// ---------------------------------------------------------------------------
__global__ __launch_bounds__(256) void softmax_k(const float* __restrict__ logits,
                                                 float* __restrict__ out, int N) {
    int lane = threadIdx.x & 63;
    int n = (blockIdx.x * blockDim.x + threadIdx.x) >> 6;
    if (n >= N) return;
    float lg = (lane < N_CLS) ? logits[(size_t)n * N_CLS + lane] : -INFINITY;
    float m = wave_max_f(lg);
    float p = (lane < N_CLS) ? __expf(lg - m) : 0.f;
    float s = wave_sum_f(p);
    if (lane < N_CLS) out[(size_t)n * N_CLS + lane] = p / s;
}

// ---------------------------------------------------------------------------
extern "C" void kernel_launch(void* const* d_in, const int* in_sizes, int n_in,
                              void* d_out, int out_size, void* d_ws, size_t ws_size,
                              hipStream_t stream) {
    const int N = NN, E = EE, E2 = EE + NN;
    const float* x    = (const float*)d_in[0];
    const int*   ei   = (const int*)d_in[1];
    const float* W1   = (const float*)d_in[2];
    const float* as1  = (const float*)d_in[3];
    const float* ad1  = (const float*)d_in[4];
    const float* b1   = (const float*)d_in[5];
    const float* W2   = (const float*)d_in[6];
    const float* as2  = (const float*)d_in[7];
    const float* ad2  = (const float*)d_in[8];
    const float* b2   = (const float*)d_in[9];
    const float* W3   = (const float*)d_in[10];
    const float* as3  = (const float*)d_in[11];
    const float* ad3  = (const float*)d_in[12];
    const float* b3   = (const float*)d_in[13];
    const float* bn1g = (const float*)d_in[14];
    const float* bn1b = (const float*)d_in[15];
    const float* bn1m = (const float*)d_in[16];
    const float* bn1v = (const float*)d_in[17];
    const float* bn2g = (const float*)d_in[18];
    const float* bn2b = (const float*)d_in[19];
    const float* bn2m = (const float*)d_in[20];
    const float* bn2v = (const float*)d_in[21];
    const float* cW1  = (const float*)d_in[22];
    const float* cb1  = (const float*)d_in[23];
    const float* cW2  = (const float*)d_in[24];
    const float* cb2  = (const float*)d_in[25];
    float* out = (float*)d_out;

    char* ws = (char*)d_ws;
    size_t off = 0;
    auto alloc = [&](size_t bytes) {
        void* p = ws + off;
        off = (off + bytes + 255) & ~(size_t)255;
        return p;
    };
    int*   rowptr = (int*)alloc((size_t)(N + 1) * 4);
    int*   cursor = (int*)alloc((size_t)N * 4);
    int*   excl   = (int*)alloc((size_t)N * 4);
    int*   bsum   = (int*)alloc(64 * 4);
    int*   csr    = (int*)alloc((size_t)E2 * 4);
    unsigned short* hbf = (unsigned short*)alloc((size_t)N * 512 * 2);  // bf16 h
    float* asb    = (float*)alloc((size_t)N * 8 * 4);
    float* adb    = (float*)alloc((size_t)N * 8 * 4);
    float* as3b   = (float*)alloc((size_t)N * 4);
    float* ad3b   = (float*)alloc((size_t)N * 4);
    unsigned short* xh  = (unsigned short*)alloc((size_t)N * 256 * 2);
    unsigned short* xl  = (unsigned short*)alloc((size_t)N * 256 * 2);
    unsigned short* f1h = (unsigned short*)alloc((size_t)N * 64 * 2);
    unsigned short* f1l = (unsigned short*)alloc((size_t)N * 64 * 2);
    unsigned short* f2h = (unsigned short*)alloc((size_t)N * 64 * 2);
    unsigned short* f3h = (unsigned short*)alloc((size_t)N * 64 * 2);
    unsigned short* f3l = (unsigned short*)alloc((size_t)N * 64 * 2);
    unsigned short* zh  = (unsigned short*)alloc((size_t)N * 64 * 2);
    unsigned short* zl  = (unsigned short*)alloc((size_t)N * 64 * 2);
    unsigned short* w1h = (unsigned short*)alloc((size_t)131072 * 2);
    unsigned short* w1l = (unsigned short*)alloc((size_t)131072 * 2);
    unsigned short* w2h = (unsigned short*)alloc(16384 * 2);
    unsigned short* w2l = (unsigned short*)alloc(16384 * 2);
    unsigned short* wch = (unsigned short*)alloc(4096 * 2);
    unsigned short* wcl = (unsigned short*)alloc(4096 * 2);
    unsigned short* wlh = (unsigned short*)alloc(3200 * 2);
    unsigned short* wll = (unsigned short*)alloc(3200 * 2);
    float* sc1 = (float*)alloc(64 * 4);
    float* sh1 = (float*)alloc(64 * 4);
    float* sc2 = (float*)alloc(64 * 4);
    float* sh2 = (float*)alloc(64 * 4);
    float* Wc    = (float*)alloc(64 * 64 * 4);
    float* w_as3 = (float*)alloc(64 * 4);
    float* w_ad3 = (float*)alloc(64 * 4);
    float* bc    = (float*)alloc(64 * 4);
    float* logits = (float*)alloc((size_t)N * N_CLS * 4);

    const int NB = (N + 1023) / 1024;        // 49 scan blocks

    // ---- CSR build (parallel scan) + folds + conversions (x + weights) ----
    hipMemsetAsync(cursor, 0, (size_t)N * 4, stream);
    count_k<<<(E2 + 255) / 256, 256, 0, stream>>>(ei, cursor, E, N);
    scan1_k<<<NB, 1024, 0, stream>>>(cursor, excl, bsum, N);
    scan2_k<<<1, 64, 0, stream>>>(bsum, NB);
    scan3_k<<<(N + 255) / 256, 256, 0, stream>>>(excl, bsum, rowptr, N, E2);
    hipMemsetAsync(cursor, 0, (size_t)N * 4, stream);
    fill_k<<<(E2 + 255) / 256, 256, 0, stream>>>(ei, rowptr, cursor, csr, E, N);
    prep_k<<<66, 64, 0, stream>>>(W3, cW1, as3, ad3, b3, cb1,
                                  bn1g, bn1b, bn1m, bn1v, b1,
                                  bn2g, bn2b, bn2m, bn2v, b2,
                                  Wc, w_as3, w_ad3, bc, sc1, sh1, sc2, sh2);
    cvt_all_k<<<(S_WL + 255) / 256, 256, 0, stream>>>(x, W1, W2, Wc, cW2,
        xh, xl, w1h, w1l, w2h, w2l, wch, wcl, wlh, wll);

    const int MB = (N + 63) / 64;
    const int AB = (N + 3) / 4;

    // ---- Layer 1: heads=8, in=256 (pre-converted split-bf16 A) ----
    gemm_mfma_k<<<dim3(4, MB), 256, 0, stream>>>(xh, xl, w1h, w1l,
        nullptr, hbf, nullptr, N, 512, 256, nullptr, 0, as1, ad1, asb, adb, 8);
    agg_k<8, true><<<AB, 256, 0, stream>>>(hbf, asb, adb, rowptr, csr, sc1, sh1,
        f1h, f1l, nullptr, nullptr, nullptr, nullptr, N);

    // ---- Layer 2: heads=4, in=64; agg2 also emits layer-3 scores ----
    gemm_mfma_k<<<dim3(2, MB), 256, 0, stream>>>(f1h, f1l, w2h, w2l,
        nullptr, hbf, nullptr, N, 256, 64, nullptr, 0, as2, ad2, asb, adb, 4);
    agg_k<4, true><<<AB, 256, 0, stream>>>(hbf, asb, adb, rowptr, csr, sc2, sh2,
        f2h, nullptr, w_as3, w_ad3, as3b, ad3b, N);

    // ---- Layer 3 + classifier-1 merged (r13-verified commutation) ----
    agg_k<1, false><<<AB, 256, 0, stream>>>(f2h, as3b, ad3b, rowptr, csr, nullptr, nullptr,
        f3h, f3l, nullptr, nullptr, nullptr, nullptr, N);
    gemm_mfma_k<<<dim3(1, MB), 256, 0, stream>>>(f3h, f3l, wch, wcl,
        nullptr, zh, zl, N, 64, 64, bc, 1, nullptr, nullptr, nullptr, nullptr, 0);

    // ---- logits + softmax ----
    gemm_mfma_k<<<dim3(1, MB), 256, 0, stream>>>(zh, zl, wlh, wll,
        logits, nullptr, nullptr, N, N_CLS, 64, cb2, 0, nullptr, nullptr, nullptr, nullptr, 0);
    softmax_k<<<(N + 3) / 4, 256, 0, stream>>>(logits, out, N);
}

// Round 17
// 439.227 us; speedup vs baseline: 1.0923x; 1.0923x over previous
//
#include <hip/hip_runtime.h>
#include <hip/hip_bf16.h>
#include <math.h>

#define NN 50000
#define EE 400000
#define D_IN 256
#define D_H 64
#define N_CLS 50

typedef __attribute__((ext_vector_type(8))) short bfrag;   // 8 bf16 (4 VGPR)
typedef __attribute__((ext_vector_type(4))) float ffrag;   // MFMA C/D
typedef __attribute__((ext_vector_type(8))) unsigned short u16x8_t;
typedef __attribute__((ext_vector_type(4))) unsigned short u16x4_t;

__device__ __forceinline__ unsigned short f2bf(float v) {
    unsigned int u = __float_as_uint(v);
    unsigned int r = (u + 0x7fffu + ((u >> 16) & 1u)) >> 16;   // RNE
    return (unsigned short)r;
}
__device__ __forceinline__ float bf2f(unsigned short b) {
    return __uint_as_float(((unsigned int)b) << 16);
}

// XOR sub-chunk swizzle (r7/r10-verified: 0 bank conflicts). row stride 32
// shorts (64B, unpadded); q = 8-short chunk 0..3. 16B-aligned offsets.
__device__ __forceinline__ int swz(int row, int q) {
    return row * 32 + ((q ^ ((row >> 1) & 3)) << 3);
}

// ---------------------------------------------------------------------------
// CSR construction — parallel 3-phase scan (verified r7)
// ---------------------------------------------------------------------------
__global__ void count_k(const int* __restrict__ ei, int* __restrict__ cnt, int E, int N) {
    int i = blockIdx.x * blockDim.x + threadIdx.x;
    if (i >= E + N) return;
    int dst = (i < E) ? ei[E + i] : (i - E);
    atomicAdd(&cnt[dst], 1);
}

__global__ __launch_bounds__(1024) void scan1_k(const int* __restrict__ counts,
                                                int* __restrict__ excl,
                                                int* __restrict__ bsum, int n) {
    __shared__ int wsum[16];
    int t = threadIdx.x;
    int lane = t & 63, wid = t >> 6;
    int idx = blockIdx.x * 1024 + t;
    int v = (idx < n) ? counts[idx] : 0;
    int incl = v;
    #pragma unroll
    for (int off = 1; off < 64; off <<= 1) {
        int x = __shfl_up(incl, off);
        if (lane >= off) incl += x;
    }
    if (lane == 63) wsum[wid] = incl;
    __syncthreads();
    if (wid == 0) {
        int ws = (lane < 16) ? wsum[lane] : 0;
        int wincl = ws;
        #pragma unroll
        for (int off = 1; off < 16; off <<= 1) {
            int x = __shfl_up(wincl, off);
            if (lane >= off) wincl += x;
        }
        if (lane < 16) wsum[lane] = wincl - ws;   // exclusive wave prefix
    }
    __syncthreads();
    if (idx < n) excl[idx] = wsum[wid] + (incl - v);
    if (t == 1023) bsum[blockIdx.x] = wsum[15] + incl;
}

__global__ void scan2_k(int* __restrict__ bsum, int nb) {
    int lane = threadIdx.x & 63;
    int v = (lane < nb) ? bsum[lane] : 0;
    int incl = v;
    #pragma unroll
    for (int off = 1; off < 64; off <<= 1) {
        int x = __shfl_up(incl, off);
        if (lane >= off) incl += x;
    }
    if (lane < nb) bsum[lane] = incl - v;
}

__global__ void scan3_k(const int* __restrict__ excl, const int* __restrict__ bsum,
                        int* __restrict__ rowptr, int n, int total) {
    int i = blockIdx.x * 256 + threadIdx.x;
    if (i < n) rowptr[i] = excl[i] + bsum[i >> 10];
    if (i == 0) rowptr[n] = total;
}

__global__ void fill_k(const int* __restrict__ ei, const int* __restrict__ rowptr,
                       int* __restrict__ cursor, int* __restrict__ csr, int E, int N) {
    int i = blockIdx.x * blockDim.x + threadIdx.x;
    if (i >= E + N) return;
    int s, d;
    if (i < E) { s = ei[i]; d = ei[E + i]; }
    else       { s = i - E; d = i - E; }
    int pos = atomicAdd(&cursor[d], 1);
    csr[rowptr[d] + pos] = s;
}

// ---------------------------------------------------------------------------
// prep_k: blocks 0..63 — Wc = W3@cW1, bc = b3@cW1+cb1, w_as3/w_ad3 = W3@as3/ad3
// (agg/GEMM commute, verified r13); block 64/65 — BN folds for layers 1/2.
// ---------------------------------------------------------------------------
__global__ __launch_bounds__(64) void prep_k(
    const float* __restrict__ W3, const float* __restrict__ cW1,
    const float* __restrict__ as3, const float* __restrict__ ad3,
    const float* __restrict__ b3, const float* __restrict__ cb1,
    const float* __restrict__ bn1g, const float* __restrict__ bn1b,
    const float* __restrict__ bn1m, const float* __restrict__ bn1v,
    const float* __restrict__ b1,
    const float* __restrict__ bn2g, const float* __restrict__ bn2b,
    const float* __restrict__ bn2m, const float* __restrict__ bn2v,
    const float* __restrict__ b2,
    float* __restrict__ Wc, float* __restrict__ w_as3,
    float* __restrict__ w_ad3, float* __restrict__ bc,
    float* __restrict__ sc1, float* __restrict__ sh1,
    float* __restrict__ sc2, float* __restrict__ sh2) {
    int bj = blockIdx.x;
    int i = threadIdx.x;
    if (bj < 64) {
        int j = bj;
        float s = 0.f;
        for (int k = 0; k < 64; k++) s += W3[i * 64 + k] * cW1[k * 64 + j];
        Wc[i * 64 + j] = s;
        if (j == 0) {
            float sa = 0.f, sd = 0.f;
            for (int c = 0; c < 64; c++) {
                sa += W3[i * 64 + c] * as3[c];
                sd += W3[i * 64 + c] * ad3[c];
            }
            w_as3[i] = sa;
            w_ad3[i] = sd;
        }
        if (i == 0) {
            float s2 = 0.f;
            for (int k = 0; k < 64; k++) s2 += b3[k] * cW1[k * 64 + j];
            bc[j] = s2 + cb1[j];
        }
    } else if (bj == 64) {
        float sc = bn1g[i] * rsqrtf(bn1v[i] + 1e-5f);
        sc1[i] = sc;
        sh1[i] = (b1[i] - bn1m[i]) * sc + bn1b[i];
    } else {
        float sc = bn2g[i] * rsqrtf(bn2v[i] + 1e-5f);
        sc2[i] = sc;
        sh2[i] = (b2[i] - bn2m[i]) * sc + bn2b[i];
    }
}

// ---------------------------------------------------------------------------
// cvt_all_k: one launch converts all 4 weight matrices to split-bf16 B^T.
// Segments: W1 (256x512), W2 (64x256), Wc (64x64), cW2 (64x50).
// ---------------------------------------------------------------------------
#define S_W1 131072
#define S_W2 (S_W1 + 16384)
#define S_WC (S_W2 + 4096)
#define S_WL (S_WC + 3200)
__global__ void cvt_all_k(
    const float* __restrict__ W1, const float* __restrict__ W2,
    const float* __restrict__ Wc, const float* __restrict__ cW2,
    unsigned short* __restrict__ w1h, unsigned short* __restrict__ w1l,
    unsigned short* __restrict__ w2h, unsigned short* __restrict__ w2l,
    unsigned short* __restrict__ wch, unsigned short* __restrict__ wcl,
    unsigned short* __restrict__ wlh, unsigned short* __restrict__ wll) {
    int i = blockIdx.x * 256 + threadIdx.x;
    const float* src; unsigned short* dh; unsigned short* dl;
    int K, Nn, j;
    if (i < S_W1)      { j = i;        src = W1;  dh = w1h; dl = w1l; K = 256; Nn = 512; }
    else if (i < S_W2) { j = i - S_W1; src = W2;  dh = w2h; dl = w2l; K = 64;  Nn = 256; }
    else if (i < S_WC) { j = i - S_W2; src = Wc;  dh = wch; dl = wcl; K = 64;  Nn = 64;  }
    else if (i < S_WL) { j = i - S_WC; src = cW2; dh = wlh; dl = wll; K = 64;  Nn = 50;  }
    else return;
    int k = j / Nn, n = j - k * Nn;
    float v = src[j];
    unsigned short h = f2bf(v);
    dh[(size_t)n * K + k] = h;
    dl[(size_t)n * K + k] = f2bf(v - bf2f(h));
}

// ---------------------------------------------------------------------------
// Split-bf16 MFMA GEMM (r15 config — best measured total). Optional fused
// fp32-A split (layer 1). 64x128 tile, BK=32, 4 waves 2x2, conflict-free
// XOR LDS. Fused epilogues: fp32/bf16(+lo) C, bias+ReLU, attention scores.
// ---------------------------------------------------------------------------
__global__ __launch_bounds__(256) void gemm_mfma_k(
    const float* __restrict__ Af,
    const unsigned short* __restrict__ Ahi, const unsigned short* __restrict__ Alo,
    const unsigned short* __restrict__ BThi, const unsigned short* __restrict__ BTlo,
    float* __restrict__ Cf, unsigned short* __restrict__ Chi, unsigned short* __restrict__ Clo,
    int M, int N, int K,
    const float* __restrict__ bias, int do_relu,
    const float* __restrict__ att_s, const float* __restrict__ att_d,
    float* __restrict__ asb, float* __restrict__ adb, int H) {
    __shared__ unsigned short sAh[64 * 32];
    __shared__ unsigned short sAl[64 * 32];
    __shared__ unsigned short sBh[128 * 32];
    __shared__ unsigned short sBl[128 * 32];
    const int tid = threadIdx.x;
    const int m0 = blockIdx.y * 64;
    const int n0 = blockIdx.x * 128;
    const int lane = tid & 63, w = tid >> 6;
    const int wm = w >> 1, wn = w & 1;
    const int c16 = lane & 15, kq = lane >> 4;
    const int arow = tid >> 2;          // 0..63
    const int q    = tid & 3;           // 8-short chunk 0..3
    const int akc  = q * 8;
    const int aM  = min(m0 + arow, M - 1);
    const int bn0 = min(n0 + arow, N - 1);
    const int bn1 = min(n0 + 64 + arow, N - 1);
    const int wA  = swz(arow, q);
    const int wB0 = swz(arow, q);
    const int wB1 = swz(64 + arow, q);
    const float* pAf          = Af  ? Af  + (size_t)aM * K + akc : nullptr;
    const unsigned short* pAh = Ahi ? Ahi + (size_t)aM * K + akc : nullptr;
    const unsigned short* pAl = Alo ? Alo + (size_t)aM * K + akc : nullptr;
    const unsigned short* pBh0 = BThi + (size_t)bn0 * K + akc;
    const unsigned short* pBl0 = BTlo + (size_t)bn0 * K + akc;
    const unsigned short* pBh1 = BThi + (size_t)bn1 * K + akc;
    const unsigned short* pBl1 = BTlo + (size_t)bn1 * K + akc;
    ffrag acc[2][4] = {};

    for (int k0 = 0; k0 < K; k0 += 32) {
        bfrag va_h, va_l;
        if (Af) {
            float4 f0 = *(const float4*)(pAf + k0);
            float4 f1 = *(const float4*)(pAf + k0 + 4);
            float fv[8] = {f0.x, f0.y, f0.z, f0.w, f1.x, f1.y, f1.z, f1.w};
            #pragma unroll
            for (int i = 0; i < 8; i++) {
                unsigned short hh = f2bf(fv[i]);
                va_h[i] = (short)hh;
                va_l[i] = (short)f2bf(fv[i] - bf2f(hh));
            }
        } else {
            va_h = *(const bfrag*)(pAh + k0);
            va_l = *(const bfrag*)(pAl + k0);
        }
        bfrag vb_h0 = *(const bfrag*)(pBh0 + k0);
        bfrag vb_l0 = *(const bfrag*)(pBl0 + k0);
        bfrag vb_h1 = *(const bfrag*)(pBh1 + k0);
        bfrag vb_l1 = *(const bfrag*)(pBl1 + k0);
        __syncthreads();
        *(bfrag*)&sAh[wA]  = va_h;
        *(bfrag*)&sAl[wA]  = va_l;
        *(bfrag*)&sBh[wB0] = vb_h0;
        *(bfrag*)&sBl[wB0] = vb_l0;
        *(bfrag*)&sBh[wB1] = vb_h1;
        *(bfrag*)&sBl[wB1] = vb_l1;
        __syncthreads();
        bfrag ah[2], al_[2], bh[4], bl[4];
        #pragma unroll
        for (int mt = 0; mt < 2; mt++) {
            int ra = wm * 32 + mt * 16 + c16;
            ah[mt]  = *(const bfrag*)&sAh[swz(ra, kq)];
            al_[mt] = *(const bfrag*)&sAl[swz(ra, kq)];
        }
        #pragma unroll
        for (int nt = 0; nt < 4; nt++) {
            int rb = wn * 64 + nt * 16 + c16;
            bh[nt] = *(const bfrag*)&sBh[swz(rb, kq)];
            bl[nt] = *(const bfrag*)&sBl[swz(rb, kq)];
        }
        #pragma unroll
        for (int mt = 0; mt < 2; mt++)
            #pragma unroll
            for (int nt = 0; nt < 4; nt++) {
                acc[mt][nt] = __builtin_amdgcn_mfma_f32_16x16x32_bf16(ah[mt],  bh[nt], acc[mt][nt], 0, 0, 0);
                acc[mt][nt] = __builtin_amdgcn_mfma_f32_16x16x32_bf16(ah[mt],  bl[nt], acc[mt][nt], 0, 0, 0);
                acc[mt][nt] = __builtin_amdgcn_mfma_f32_16x16x32_bf16(al_[mt], bh[nt], acc[mt][nt], 0, 0, 0);
            }
    }

    // ---- fused attention scores (raw h, pre-bias/relu; GAT layers only) ----
    if (att_s) {
        int hidx = n0 / 64 + wn;
        if (hidx < H) {
            float s_att[4], d_att[4];
            #pragma unroll
            for (int nt = 0; nt < 4; nt++) {
                s_att[nt] = att_s[hidx * 64 + nt * 16 + c16];
                d_att[nt] = att_d[hidx * 64 + nt * 16 + c16];
            }
            #pragma unroll
            for (int mt = 0; mt < 2; mt++) {
                #pragma unroll
                for (int r = 0; r < 4; r++) {
                    int row = m0 + wm * 32 + mt * 16 + kq * 4 + r;
                    float ps = 0.f, pd = 0.f;
                    #pragma unroll
                    for (int nt = 0; nt < 4; nt++) {
                        ps = fmaf(acc[mt][nt][r], s_att[nt], ps);
                        pd = fmaf(acc[mt][nt][r], d_att[nt], pd);
                    }
                    #pragma unroll
                    for (int msk = 1; msk < 16; msk <<= 1) {
                        ps += __shfl_xor(ps, msk);
                        pd += __shfl_xor(pd, msk);
                    }
                    if (c16 == 0 && row < M) {
                        asb[(size_t)row * H + hidx] = ps;
                        adb[(size_t)row * H + hidx] = pd;
                    }
                }
            }
        }
    }

    // ---- C write ----
    #pragma unroll
    for (int mt = 0; mt < 2; mt++) {
        #pragma unroll
        for (int r = 0; r < 4; r++) {
            int row = m0 + wm * 32 + mt * 16 + kq * 4 + r;
            if (row < M) {
                #pragma unroll
                for (int nt = 0; nt < 4; nt++) {
                    int col = n0 + wn * 64 + nt * 16 + c16;
                    if (col < N) {
                        float v = acc[mt][nt][r];
                        if (bias) v += bias[col];
                        if (do_relu) v = fmaxf(v, 0.f);
                        size_t idx = (size_t)row * N + col;
                        if (Cf) Cf[idx] = v;
                        if (Chi) {
                            unsigned short hh = f2bf(v);
                            Chi[idx] = hh;
                            if (Clo) Clo[idx] = f2bf(v - bf2f(hh));
                        }
                    }
                }
            }
        }
    }
}

// ---------------------------------------------------------------------------
// Fused classifier: z = relu(f3 @ Wc + bc); probs = softmax(z @ cW2 + cb2).
// One 64-row block, 4 waves each owning 16 rows. Stage 1: direct-load MFMA
// (K=64, zero A-reuse -> no staging), z parked in LDS fp32. Stage 2: z
// re-split from LDS, MFMA vs cW2^T (L1-hot), softmax in-register via
// 16-lane xor-shuffles (logit row = 16 c16-lanes x 4 nt regs), write probs.
// ---------------------------------------------------------------------------
__global__ __launch_bounds__(256) void cls_fused_k(
    const unsigned short* __restrict__ Ah, const unsigned short* __restrict__ Al,
    const unsigned short* __restrict__ Bh1, const unsigned short* __restrict__ Bl1,
    const float* __restrict__ bias1,
    const unsigned short* __restrict__ Bh2, const unsigned short* __restrict__ Bl2,
    const float* __restrict__ bias2,
    float* __restrict__ out, int M) {
    __shared__ float zs[64][65];
    const int tid = threadIdx.x;
    const int lane = tid & 63, w = tid >> 6;
    const int c16 = lane & 15, kq = lane >> 4;
    const int m0 = blockIdx.x * 64;
    const int arow = min(m0 + w * 16 + c16, M - 1);

    // ---- stage 1: z rows w*16..w*16+15 ----
    ffrag acc1[4] = {};
    #pragma unroll
    for (int kit = 0; kit < 2; kit++) {
        int kb = kit * 32 + kq * 8;
        bfrag ah  = *(const bfrag*)(Ah + (size_t)arow * 64 + kb);
        bfrag al_ = *(const bfrag*)(Al + (size_t)arow * 64 + kb);
        #pragma unroll
        for (int nt = 0; nt < 4; nt++) {
            int bcol = nt * 16 + c16;
            bfrag bh = *(const bfrag*)(Bh1 + (size_t)bcol * 64 + kb);
            bfrag bl = *(const bfrag*)(Bl1 + (size_t)bcol * 64 + kb);
            acc1[nt] = __builtin_amdgcn_mfma_f32_16x16x32_bf16(ah,  bh, acc1[nt], 0, 0, 0);
            acc1[nt] = __builtin_amdgcn_mfma_f32_16x16x32_bf16(ah,  bl, acc1[nt], 0, 0, 0);
            acc1[nt] = __builtin_amdgcn_mfma_f32_16x16x32_bf16(al_, bh, acc1[nt], 0, 0, 0);
        }
    }
    #pragma unroll
    for (int nt = 0; nt < 4; nt++)
        #pragma unroll
        for (int r = 0; r < 4; r++) {
            int row = w * 16 + kq * 4 + r;
            int col = nt * 16 + c16;
            zs[row][col] = fmaxf(acc1[nt][r] + bias1[col], 0.f);
        }
    __syncthreads();

    // ---- stage 2: logits + softmax ----
    ffrag acc2[4] = {};
    #pragma unroll
    for (int kit = 0; kit < 2; kit++) {
        int kb = kit * 32 + kq * 8;
        float fv[8];
        #pragma unroll
        for (int i = 0; i < 8; i++) fv[i] = zs[w * 16 + c16][kb + i];
        bfrag ah, al_;
        #pragma unroll
        for (int i = 0; i < 8; i++) {
            unsigned short hh = f2bf(fv[i]);
            ah[i]  = (short)hh;
            al_[i] = (short)f2bf(fv[i] - bf2f(hh));
        }
        #pragma unroll
        for (int nt = 0; nt < 4; nt++) {
            int bcol = min(nt * 16 + c16, N_CLS - 1);
            bfrag bh = *(const bfrag*)(Bh2 + (size_t)bcol * 64 + kb);
            bfrag bl = *(const bfrag*)(Bl2 + (size_t)bcol * 64 + kb);
            acc2[nt] = __builtin_amdgcn_mfma_f32_16x16x32_bf16(ah,  bh, acc2[nt], 0, 0, 0);
            acc2[nt] = __builtin_amdgcn_mfma_f32_16x16x32_bf16(ah,  bl, acc2[nt], 0, 0, 0);
            acc2[nt] = __builtin_amdgcn_mfma_f32_16x16x32_bf16(al_, bh, acc2[nt], 0, 0, 0);
        }
    }
    #pragma unroll
    for (int r = 0; r < 4; r++) {
        int row = m0 + w * 16 + kq * 4 + r;
        float lg[4], mx = -INFINITY;
        #pragma unroll
        for (int nt = 0; nt < 4; nt++) {
            int col = nt * 16 + c16;
            lg[nt] = (col < N_CLS) ? acc2[nt][r] + bias2[col] : -INFINITY;
            mx = fmaxf(mx, lg[nt]);
        }
        #pragma unroll
        for (int msk = 1; msk < 16; msk <<= 1) mx = fmaxf(mx, __shfl_xor(mx, msk));
        float p[4], ps = 0.f;
        #pragma unroll
        for (int nt = 0; nt < 4; nt++) {
            p[nt] = (nt * 16 + c16 < N_CLS) ? __expf(lg[nt] - mx) : 0.f;
            ps += p[nt];
        }
        #pragma unroll
        for (int msk = 1; msk < 16; msk <<= 1) ps += __shfl_xor(ps, msk);
        float invs = 1.f / ps;
        if (row < M) {
            #pragma unroll
            for (int nt = 0; nt < 4; nt++) {
                int col = nt * 16 + c16;
                if (col < N_CLS) out[(size_t)row * N_CLS + col] = p[nt] * invs;
            }
        }
    }
}

__device__ __forceinline__ float wave_max_f(float v) {
    #pragma unroll
    for (int off = 32; off; off >>= 1) v = fmaxf(v, __shfl_xor(v, off));
    return v;
}
__device__ __forceinline__ float wave_sum_f(float v) {
    #pragma unroll
    for (int off = 32; off; off >>= 1) v += __shfl_xor(v, off);
    return v;
}

// ---------------------------------------------------------------------------
// Aggregation (r11/r13-verified): one wave per node, all heads, bf16 gather;
// (edge,head)-parallel softmax, deferred normalization; optional fused
// next-layer attention scores; optional null outlo/shift.
// ---------------------------------------------------------------------------
template <int H, bool MEAN_BN>
__global__ __launch_bounds__(256) void agg_k(
    const unsigned short* __restrict__ hfeat,   // [N, H*64] bf16
    const float* __restrict__ a_s, const float* __restrict__ a_d,
    const int* __restrict__ rowptr, const int* __restrict__ csr,
    const float* __restrict__ scale,
    const float* __restrict__ shift,
    unsigned short* __restrict__ outhi, unsigned short* __restrict__ outlo,
    const float* __restrict__ was3, const float* __restrict__ wad3,
    float* __restrict__ as3o, float* __restrict__ ad3o,
    int N) {
    constexpr int OUT = H * 64;
    constexpr int F = H;          // channels per lane (gather phase)
    constexpr int G = 64 / H;     // lanes per head (gather phase)
    constexpr int EPC = 64 / H;   // edges per chunk (softmax phase)
    __shared__ float alpha_s[4][H][65];
    __shared__ int srcb[4][64];
    const int wv = threadIdx.x >> 6;
    const int lane = threadIdx.x & 63;
    const int node = blockIdx.x * 4 + wv;
    if (node >= N) return;        // no __syncthreads in this kernel — safe

    const int row = rowptr[node];
    const int deg = rowptr[node + 1] - row;
    const int hl = lane / G;      // gather-phase head of this lane

    float acc[F] = {};
    float inv = 1.f;

    if (deg <= 64) {
        // ---- softmax phase: lane = (j, h); one exp per lane ----
        const int j8 = lane / H;
        const int h8 = lane % H;
        float adn_own = a_d[(size_t)node * H + h8];
        float psum = 0.f;
        for (int c0 = 0; c0 < deg; c0 += EPC) {
            int jj = c0 + j8;
            if (jj < deg) {
                int s = csr[row + jj];
                if (h8 == 0) srcb[wv][jj] = s;
                float e = a_s[(size_t)s * H + h8] + adn_own;
                e = e > 0.f ? e : 0.2f * e;
                float p = __expf(e);
                alpha_s[wv][h8][jj] = p;
                psum += p;
            }
        }
        #pragma unroll
        for (int msk = H; msk < 64; msk <<= 1)
            psum += __shfl_xor(psum, msk);
        float invd = 1.f / (psum + 1e-16f);      // lane L holds denom of head L%H
        inv = __shfl(invd, hl);                  // lane 'hl' has h8 == hl
        asm volatile("s_waitcnt lgkmcnt(0)" ::: "memory");
        // ---- gather phase ----
        for (int jj = 0; jj < deg; jj++) {
            int ss = srcb[wv][jj];
            float al = alpha_s[wv][hl][jj];
            const unsigned short* rp = hfeat + (size_t)ss * OUT + lane * F;
            if constexpr (F == 8) {
                u16x8_t u = *(const u16x8_t*)rp;
                #pragma unroll
                for (int i = 0; i < 8; i++) acc[i] = fmaf(al, bf2f(u[i]), acc[i]);
            } else if constexpr (F == 4) {
                u16x4_t u = *(const u16x4_t*)rp;
                #pragma unroll
                for (int i = 0; i < 4; i++) acc[i] = fmaf(al, bf2f(u[i]), acc[i]);
            } else {
                acc[0] = fmaf(al, bf2f(rp[0]), acc[0]);
            }
        }
    } else {
        // ---- general path (deg > 64; essentially never for this graph) ----
        float adn[H];
        #pragma unroll
        for (int h = 0; h < H; h++) adn[h] = a_d[(size_t)node * H + h];
        float m[H];
        #pragma unroll
        for (int h = 0; h < H; h++) m[h] = -INFINITY;
        for (int c0 = 0; c0 < deg; c0 += 64) {
            int j = c0 + lane;
            if (j < deg) {
                int s2 = csr[row + j];
                #pragma unroll
                for (int h = 0; h < H; h++) {
                    float e = a_s[(size_t)s2 * H + h] + adn[h];
                    e = e > 0.f ? e : 0.2f * e;
                    m[h] = fmaxf(m[h], e);
                }
            }
        }
        #pragma unroll
        for (int h = 0; h < H; h++) m[h] = wave_max_f(m[h]);
        float dsum[H] = {};
        for (int c0 = 0; c0 < deg; c0 += 64) {
            int j = c0 + lane;
            if (j < deg) {
                int s2 = csr[row + j];
                #pragma unroll
                for (int h = 0; h < H; h++) {
                    float e = a_s[(size_t)s2 * H + h] + adn[h];
                    e = e > 0.f ? e : 0.2f * e;
                    dsum[h] += __expf(e - m[h]);
                }
            }
        }
        float dinv[H];
        #pragma unroll
        for (int h = 0; h < H; h++) dinv[h] = 1.f / (wave_sum_f(dsum[h]) + 1e-16f);
        for (int c0 = 0; c0 < deg; c0 += 64) {
            int j = c0 + lane;
            int cnt = min(64, deg - c0);
            int s = 0;
            if (j < deg) {
                s = csr[row + j];
                #pragma unroll
                for (int h = 0; h < H; h++) {
                    float e = a_s[(size_t)s * H + h] + adn[h];
                    e = e > 0.f ? e : 0.2f * e;
                    alpha_s[wv][h][lane] = __expf(e - m[h]) * dinv[h];
                }
            }
            asm volatile("s_waitcnt lgkmcnt(0)" ::: "memory");
            for (int jj = 0; jj < cnt; jj++) {
                int ss = __builtin_amdgcn_readlane(s, jj);
                float al = alpha_s[wv][hl][jj];
                const unsigned short* rp = hfeat + (size_t)ss * OUT + lane * F;
                if constexpr (F == 8) {
                    u16x8_t u = *(const u16x8_t*)rp;
                    #pragma unroll
                    for (int i = 0; i < 8; i++) acc[i] = fmaf(al, bf2f(u[i]), acc[i]);
                } else if constexpr (F == 4) {
                    u16x4_t u = *(const u16x4_t*)rp;
                    #pragma unroll
                    for (int i = 0; i < 4; i++) acc[i] = fmaf(al, bf2f(u[i]), acc[i]);
                } else {
                    acc[0] = fmaf(al, bf2f(rp[0]), acc[0]);
                }
            }
            asm volatile("s_waitcnt lgkmcnt(0)" ::: "memory");
        }
        inv = 1.f;   // alpha already normalized in this path
    }

    // ---- epilogue: deferred normalization, head-mean, BN, split write ----
    #pragma unroll
    for (int i = 0; i < F; i++) acc[i] *= inv;

    if constexpr (MEAN_BN) {
        #pragma unroll
        for (int i = 0; i < F; i++) {
            #pragma unroll
            for (int msk = G; msk < 64; msk <<= 1)
                acc[i] += __shfl_xor(acc[i], msk);
        }
        const int c0 = (lane < G) ? lane * F : 0;
        float res[F];
        if (lane < G) {
            #pragma unroll
            for (int i = 0; i < F; i++) {
                float v = fmaf(acc[i] * (1.0f / H), scale[c0 + i], shift[c0 + i]);
                res[i] = fmaxf(v, 0.f);
            }
        } else {
            #pragma unroll
            for (int i = 0; i < F; i++) res[i] = 0.f;
        }
        // fused next-layer attention scores from post-BN/ReLU row
        if (was3) {
            float ps = 0.f, pd = 0.f;
            if (lane < G) {
                #pragma unroll
                for (int i = 0; i < F; i++) {
                    ps = fmaf(res[i], was3[c0 + i], ps);
                    pd = fmaf(res[i], wad3[c0 + i], pd);
                }
            }
            #pragma unroll
            for (int msk = 1; msk < G; msk <<= 1) {
                ps += __shfl_xor(ps, msk);
                pd += __shfl_xor(pd, msk);
            }
            if (lane == 0) { as3o[node] = ps; ad3o[node] = pd; }
        }
        if (lane < G) {
            #pragma unroll
            for (int i = 0; i < F; i++) {
                unsigned short hh = f2bf(res[i]);
                outhi[(size_t)node * 64 + c0 + i] = hh;
                if (outlo) outlo[(size_t)node * 64 + c0 + i] = f2bf(res[i] - bf2f(hh));
            }
        }
    } else {
        float v = acc[0] + (shift ? shift[lane] : 0.f);
        unsigned short hh = f2bf(v);
        outhi[(size_t)node * 64 + lane] = hh;
        if (outlo) outlo[(size_t)node * 64 + lane] = f2bf(v - bf2f(hh));
    }
}

// ---------------------------------------------------------------------------
extern "C" void kernel_launch(void* const* d_in, const int* in_sizes, int n_in,
                              void* d_out, int out_size, void* d_ws, size_t ws_size,
                              hipStream_t stream) {
    const int N = NN, E = EE, E2 = EE + NN;
    const float* x    = (const float*)d_in[0];
    const int*   ei   = (const int*)d_in[1];
    const float* W1   = (const float*)d_in[2];
    const float* as1  = (const float*)d_in[3];
    const float* ad1  = (const float*)d_in[4];
    const float* b1   = (const float*)d_in[5];
    const float* W2   = (const float*)d_in[6];
    const float* as2  = (const float*)d_in[7];
    const float* ad2  = (const float*)d_in[8];
    const float* b2   = (const float*)d_in[9];
    const float* W3   = (const float*)d_in[10];
    const float* as3  = (const float*)d_in[11];
    const float* ad3  = (const float*)d_in[12];
    const float* b3   = (const float*)d_in[13];
    const float* bn1g = (const float*)d_in[14];
    const float* bn1b = (const float*)d_in[15];
    const float* bn1m = (const float*)d_in[16];
    const float* bn1v = (const float*)d_in[17];
    const float* bn2g = (const float*)d_in[18];
    const float* bn2b = (const float*)d_in[19];
    const float* bn2m = (const float*)d_in[20];
    const float* bn2v = (const float*)d_in[21];
    const float* cW1  = (const float*)d_in[22];
    const float* cb1  = (const float*)d_in[23];
    const float* cW2  = (const float*)d_in[24];
    const float* cb2  = (const float*)d_in[25];
    float* out = (float*)d_out;

    char* ws = (char*)d_ws;
    size_t off = 0;
    auto alloc = [&](size_t bytes) {
        void* p = ws + off;
        off = (off + bytes + 255) & ~(size_t)255;
        return p;
    };
    int*   rowptr = (int*)alloc((size_t)(N + 1) * 4);
    int*   cursor = (int*)alloc((size_t)N * 4);
    int*   excl   = (int*)alloc((size_t)N * 4);
    int*   bsum   = (int*)alloc(64 * 4);
    int*   csr    = (int*)alloc((size_t)E2 * 4);
    unsigned short* hbf = (unsigned short*)alloc((size_t)N * 512 * 2);  // bf16 h
    float* asb    = (float*)alloc((size_t)N * 8 * 4);
    float* adb    = (float*)alloc((size_t)N * 8 * 4);
    float* as3b   = (float*)alloc((size_t)N * 4);
    float* ad3b   = (float*)alloc((size_t)N * 4);
    unsigned short* f1h = (unsigned short*)alloc((size_t)N * 64 * 2);
    unsigned short* f1l = (unsigned short*)alloc((size_t)N * 64 * 2);
    unsigned short* f2h = (unsigned short*)alloc((size_t)N * 64 * 2);
    unsigned short* f3h = (unsigned short*)alloc((size_t)N * 64 * 2);
    unsigned short* f3l = (unsigned short*)alloc((size_t)N * 64 * 2);
    unsigned short* w1h = (unsigned short*)alloc((size_t)131072 * 2);
    unsigned short* w1l = (unsigned short*)alloc((size_t)131072 * 2);
    unsigned short* w2h = (unsigned short*)alloc(16384 * 2);
    unsigned short* w2l = (unsigned short*)alloc(16384 * 2);
    unsigned short* wch = (unsigned short*)alloc(4096 * 2);
    unsigned short* wcl = (unsigned short*)alloc(4096 * 2);
    unsigned short* wlh = (unsigned short*)alloc(3200 * 2);
    unsigned short* wll = (unsigned short*)alloc(3200 * 2);
    float* sc1 = (float*)alloc(64 * 4);
    float* sh1 = (float*)alloc(64 * 4);
    float* sc2 = (float*)alloc(64 * 4);
    float* sh2 = (float*)alloc(64 * 4);
    float* Wc    = (float*)alloc(64 * 64 * 4);
    float* w_as3 = (float*)alloc(64 * 4);
    float* w_ad3 = (float*)alloc(64 * 4);
    float* bc    = (float*)alloc(64 * 4);

    const int NB = (N + 1023) / 1024;        // 49 scan blocks

    // ---- CSR build (parallel scan) + folds + weight conversion ----
    hipMemsetAsync(cursor, 0, (size_t)N * 4, stream);
    count_k<<<(E2 + 255) / 256, 256, 0, stream>>>(ei, cursor, E, N);
    scan1_k<<<NB, 1024, 0, stream>>>(cursor, excl, bsum, N);
    scan2_k<<<1, 64, 0, stream>>>(bsum, NB);
    scan3_k<<<(N + 255) / 256, 256, 0, stream>>>(excl, bsum, rowptr, N, E2);
    hipMemsetAsync(cursor, 0, (size_t)N * 4, stream);
    fill_k<<<(E2 + 255) / 256, 256, 0, stream>>>(ei, rowptr, cursor, csr, E, N);
    prep_k<<<66, 64, 0, stream>>>(W3, cW1, as3, ad3, b3, cb1,
                                  bn1g, bn1b, bn1m, bn1v, b1,
                                  bn2g, bn2b, bn2m, bn2v, b2,
                                  Wc, w_as3, w_ad3, bc, sc1, sh1, sc2, sh2);
    cvt_all_k<<<(S_WL + 255) / 256, 256, 0, stream>>>(W1, W2, Wc, cW2,
        w1h, w1l, w2h, w2l, wch, wcl, wlh, wll);

    const int MB = (N + 63) / 64;
    const int AB = (N + 3) / 4;

    // ---- Layer 1: heads=8, in=256 (A = x fp32, manual cvt fused — r15) ----
    gemm_mfma_k<<<dim3(4, MB), 256, 0, stream>>>(x, nullptr, nullptr, w1h, w1l,
        nullptr, hbf, nullptr, N, 512, 256, nullptr, 0, as1, ad1, asb, adb, 8);
    agg_k<8, true><<<AB, 256, 0, stream>>>(hbf, asb, adb, rowptr, csr, sc1, sh1,
        f1h, f1l, nullptr, nullptr, nullptr, nullptr, N);

    // ---- Layer 2: heads=4, in=64; agg2 also emits layer-3 scores ----
    gemm_mfma_k<<<dim3(2, MB), 256, 0, stream>>>(nullptr, f1h, f1l, w2h, w2l,
        nullptr, hbf, nullptr, N, 256, 64, nullptr, 0, as2, ad2, asb, adb, 4);
    agg_k<4, true><<<AB, 256, 0, stream>>>(hbf, asb, adb, rowptr, csr, sc2, sh2,
        f2h, nullptr, w_as3, w_ad3, as3b, ad3b, N);

    // ---- Layer 3 agg (r13-verified commutation: gemm3 folded into Wc) ----
    agg_k<1, false><<<AB, 256, 0, stream>>>(f2h, as3b, ad3b, rowptr, csr, nullptr, nullptr,
        f3h, f3l, nullptr, nullptr, nullptr, nullptr, N);

    // ---- Fused classifier: z-GEMM + logits-GEMM + softmax in one kernel ----
    cls_fused_k<<<MB, 256, 0, stream>>>(f3h, f3l, wch, wcl, bc, wlh, wll, cb2, out, N);
}